// Round 1
// baseline (395.418 us; speedup 1.0000x reference)
//
#include <hip/hip_runtime.h>
#include <cmath>

// ---------------------------------------------------------------------------
// SConvNetBlock: LN1 -> SiLU -> complex-decay scan (== reference FFT conv)
//                -> *sc_lin -> +res -> LN2 -> FFN(GEMM+SiLU+GEMM) -> +res
// Design notes:
//  * sconv: c[l] = p*c[l-1] + h[l], c[-1]=last, out = Re(c).  Chunked scan:
//    32 chunks of 64; partial (zero-init) states -> sequential combine with
//    p^64 -> final scan writing x2 = x + sc*Re(c) into d_out.
//  * GEMMs in fp16 MFMA (16x16x32, fp32 acc). B^T layout: W[f][d] rows are
//    contiguous in K, same fragment addressing as A.
//  * x2 stored in d_out (fully written before LN2/GEMM2 read it).
// ---------------------------------------------------------------------------

#define DIMD 1024
#define FFD  4096
#define BATCH 4
#define SEQL 2048
#define MROWS (BATCH*SEQL)      // 8192
#define EPSF 1e-5f
#define CHUNKS 32
#define CLEN (SEQL/CHUNKS)      // 64

typedef __attribute__((ext_vector_type(8))) _Float16 half8;
typedef __attribute__((ext_vector_type(4))) _Float16 half4;
typedef __attribute__((ext_vector_type(4))) float    floatx4;

// ---- workspace layout (bytes) ----
#define H_OFF    0u                       // h   fp32 [8192][1024]   32 MB
#define E_OFF    33554432u                // e   float2 [4][32][1024] 1 MB
#define SIN_OFF  34603008u                // sin float2 [4][32][1024] 1 MB
#define H2_OFF   35651584u                // h2  fp16 [8192][1024]   16 MB
#define W1H_OFF  52428800u                // w1h fp16 [4096][1024]    8 MB
#define W2H_OFF  60817408u                // w2h fp16 [1024][4096]    8 MB
#define Y1_OFF   69206016u                // y1  fp16 [8192][4096]   64 MB
// total ~130 MB

__global__ __launch_bounds__(256)
void cast_f32_f16(const float* __restrict__ src, _Float16* __restrict__ dst) {
    int i = (blockIdx.x * 256 + threadIdx.x) * 4;
    float4 v = *(const float4*)(src + i);
    half4 o;
    o.x = (_Float16)v.x; o.y = (_Float16)v.y; o.z = (_Float16)v.z; o.w = (_Float16)v.w;
    *(half4*)(dst + i) = o;
}

// mode 1: out = silu(LN(x)) fp32 ;  mode 2: out = LN(x) fp16
__global__ __launch_bounds__(256)
void ln_kernel(const float* __restrict__ x, const float* __restrict__ w,
               const float* __restrict__ b, float* __restrict__ of,
               _Float16* __restrict__ oh, int mode) {
    const size_t row = blockIdx.x;
    const int tid = threadIdx.x;
    float4 v = *(const float4*)(x + row * DIMD + tid * 4);
    float s = (v.x + v.y) + (v.z + v.w);
    float q = (v.x * v.x + v.y * v.y) + (v.z * v.z + v.w * v.w);
    #pragma unroll
    for (int off = 32; off; off >>= 1) {
        s += __shfl_down(s, off, 64);
        q += __shfl_down(q, off, 64);
    }
    __shared__ float red[8];
    if (!(tid & 63)) { red[tid >> 6] = s; red[4 + (tid >> 6)] = q; }
    __syncthreads();
    s = (red[0] + red[1]) + (red[2] + red[3]);
    q = (red[4] + red[5]) + (red[6] + red[7]);
    const float mu = s * (1.f / DIMD);
    const float rs = rsqrtf(q * (1.f / DIMD) - mu * mu + EPSF);
    float4 wv = *(const float4*)(w + tid * 4);
    float4 bv = *(const float4*)(b + tid * 4);
    float o0 = (v.x - mu) * rs * wv.x + bv.x;
    float o1 = (v.y - mu) * rs * wv.y + bv.y;
    float o2 = (v.z - mu) * rs * wv.z + bv.z;
    float o3 = (v.w - mu) * rs * wv.w + bv.w;
    if (mode == 1) {
        o0 = o0 / (1.f + __expf(-o0));
        o1 = o1 / (1.f + __expf(-o1));
        o2 = o2 / (1.f + __expf(-o2));
        o3 = o3 / (1.f + __expf(-o3));
        float4 ov = {o0, o1, o2, o3};
        *(float4*)(of + row * DIMD + tid * 4) = ov;
    } else {
        half4 hv;
        hv.x = (_Float16)o0; hv.y = (_Float16)o1;
        hv.z = (_Float16)o2; hv.w = (_Float16)o3;
        *(half4*)(oh + row * DIMD + tid * 4) = hv;
    }
}

__device__ __forceinline__ void get_p(const float* pre, const float* pim, int d,
                                      float& pr, float& pi) {
    float re = pre[d], im = pim[d];
    float r = sqrtf(re * re + im * im);
    float t = tanhf(r) / fmaxf(r, 1e-30f);
    pr = re * t; pi = im * t;
}

// per-chunk local scan (zero initial state) -> end state e[b][c][d]
__global__ __launch_bounds__(256)
void scan_partial(const float* __restrict__ h, const float* __restrict__ pre,
                  const float* __restrict__ pim, float2* __restrict__ e) {
    const int d = blockIdx.x * 256 + threadIdx.x;
    const int c = blockIdx.y;
    const int bb = blockIdx.z;
    float pr, pi; get_p(pre, pim, d, pr, pi);
    float sr = 0.f, si = 0.f;
    const float* hp = h + ((size_t)bb * SEQL + (size_t)c * CLEN) * DIMD + d;
    #pragma unroll 4
    for (int j = 0; j < CLEN; ++j) {
        float hv = hp[(size_t)j * DIMD];
        float nr = pr * sr - pi * si + hv;
        float ni = pr * si + pi * sr;
        sr = nr; si = ni;
    }
    e[((size_t)bb * CHUNKS + c) * DIMD + d] = make_float2(sr, si);
}

// sequential combine over chunks: sin[b][c][d] = state entering chunk c
__global__ __launch_bounds__(256)
void scan_combine(const float2* __restrict__ e, const float* __restrict__ pre,
                  const float* __restrict__ pim, const float* __restrict__ lre,
                  const float* __restrict__ lim, float2* __restrict__ sv) {
    const int d = blockIdx.x * 256 + threadIdx.x;
    const int bb = blockIdx.y;
    float pr, pi; get_p(pre, pim, d, pr, pi);
    float qr = pr, qi = pi;                 // p^64 via 6 squarings
    #pragma unroll
    for (int s = 0; s < 6; ++s) {
        float nr = qr * qr - qi * qi;
        float ni = 2.f * qr * qi;
        qr = nr; qi = ni;
    }
    float sr = lre[d], si = lim[d];
    for (int c = 0; c < CHUNKS; ++c) {
        sv[((size_t)bb * CHUNKS + c) * DIMD + d] = make_float2(sr, si);
        float2 ec = e[((size_t)bb * CHUNKS + c) * DIMD + d];
        float nr = qr * sr - qi * si + ec.x;
        float ni = qr * si + qi * sr + ec.y;
        sr = nr; si = ni;
    }
}

// final scan with true incoming state; x2 = x + sc*Re(c) -> d_out
__global__ __launch_bounds__(256)
void scan_final(const float* __restrict__ h, const float* __restrict__ x,
                const float* __restrict__ pre, const float* __restrict__ pim,
                const float* __restrict__ sc, const float2* __restrict__ sv,
                float* __restrict__ x2) {
    const int d = blockIdx.x * 256 + threadIdx.x;
    const int c = blockIdx.y;
    const int bb = blockIdx.z;
    float pr, pi; get_p(pre, pim, d, pr, pi);
    float2 s0 = sv[((size_t)bb * CHUNKS + c) * DIMD + d];
    float sr = s0.x, si = s0.y;
    const float scd = sc[d];
    const size_t base = ((size_t)bb * SEQL + (size_t)c * CLEN) * DIMD + d;
    #pragma unroll 4
    for (int j = 0; j < CLEN; ++j) {
        float hv = h[base + (size_t)j * DIMD];
        float nr = pr * sr - pi * si + hv;
        float ni = pr * si + pi * sr;
        sr = nr; si = ni;
        x2[base + (size_t)j * DIMD] = x[base + (size_t)j * DIMD] + scd * sr;
    }
}

// ---- GEMM: C[M][N] = A[M][K] * W[N][K]^T, fp16 in, fp32 acc ----
#define BM 128
#define BN 128
#define BK 64
#define LDT 72   // padded LDS leading dim (bank-conflict free: 2-way only)

__global__ __launch_bounds__(256)
void gemm_bt(const _Float16* __restrict__ A, const _Float16* __restrict__ W,
             const float* __restrict__ bias, _Float16* __restrict__ out_h,
             const float* resid, float* out_f, int N, int K, int epi) {
    __shared__ _Float16 As[BM * LDT];
    __shared__ _Float16 Bs[BN * LDT];
    const int tid  = threadIdx.x;
    const int lane = tid & 63;
    const int wave = tid >> 6;
    const int wm = (wave >> 1) * 64;
    const int wn = (wave & 1) * 64;
    const size_t m0 = (size_t)blockIdx.y * BM;
    const size_t n0 = (size_t)blockIdx.x * BN;
    const int lrow = tid >> 3;
    const int lkc  = (tid & 7) * 8;
    const int fr = lane & 15;
    const int fq = (lane >> 4) * 8;

    floatx4 acc[4][4] = {};

    for (int k0 = 0; k0 < K; k0 += BK) {
        #pragma unroll
        for (int p = 0; p < 4; ++p) {
            const int row = p * 32 + lrow;
            *(uint4*)(&As[row * LDT + lkc]) =
                *(const uint4*)(A + (m0 + row) * K + k0 + lkc);
            *(uint4*)(&Bs[row * LDT + lkc]) =
                *(const uint4*)(W + (n0 + row) * K + k0 + lkc);
        }
        __syncthreads();
        #pragma unroll
        for (int kk = 0; kk < BK; kk += 32) {
            half8 af[4], bf[4];
            #pragma unroll
            for (int i = 0; i < 4; ++i) {
                af[i] = *(const half8*)(&As[(wm + i * 16 + fr) * LDT + kk + fq]);
                bf[i] = *(const half8*)(&Bs[(wn + i * 16 + fr) * LDT + kk + fq]);
            }
            #pragma unroll
            for (int i = 0; i < 4; ++i)
                #pragma unroll
                for (int j = 0; j < 4; ++j)
                    acc[i][j] = __builtin_amdgcn_mfma_f32_16x16x32_f16(
                        af[i], bf[j], acc[i][j], 0, 0, 0);
        }
        __syncthreads();
    }

    const int quad = lane >> 4;
    #pragma unroll
    for (int i = 0; i < 4; ++i) {
        #pragma unroll
        for (int j = 0; j < 4; ++j) {
            #pragma unroll
            for (int r = 0; r < 4; ++r) {
                const size_t gm = m0 + wm + i * 16 + quad * 4 + r;
                const size_t gn = n0 + wn + j * 16 + fr;
                float v = acc[i][j][r] + bias[gn];
                if (epi == 1) {
                    float sl = v / (1.f + __expf(-v));
                    out_h[gm * N + gn] = (_Float16)sl;
                } else {
                    out_f[gm * N + gn] = v + resid[gm * N + gn];
                }
            }
        }
    }
}

extern "C" void kernel_launch(void* const* d_in, const int* in_sizes, int n_in,
                              void* d_out, int out_size, void* d_ws, size_t ws_size,
                              hipStream_t stream) {
    const float* x    = (const float*)d_in[0];
    const float* ln1w = (const float*)d_in[1];
    const float* ln1b = (const float*)d_in[2];
    const float* ln2w = (const float*)d_in[3];
    const float* ln2b = (const float*)d_in[4];
    const float* sc   = (const float*)d_in[5];
    const float* pre  = (const float*)d_in[6];
    const float* pim  = (const float*)d_in[7];
    const float* lre  = (const float*)d_in[8];
    const float* lim  = (const float*)d_in[9];
    const float* w1   = (const float*)d_in[10];
    const float* b1   = (const float*)d_in[11];
    const float* w2   = (const float*)d_in[12];
    const float* b2   = (const float*)d_in[13];

    char* ws = (char*)d_ws;
    float*      h   = (float*)(ws + H_OFF);
    float2*     e   = (float2*)(ws + E_OFF);
    float2*     sv  = (float2*)(ws + SIN_OFF);
    _Float16*   h2  = (_Float16*)(ws + H2_OFF);
    _Float16*   w1h = (_Float16*)(ws + W1H_OFF);
    _Float16*   w2h = (_Float16*)(ws + W2H_OFF);
    _Float16*   y1  = (_Float16*)(ws + Y1_OFF);
    float*      x2  = (float*)d_out;
    float*      outp = (float*)d_out;

    cast_f32_f16<<<dim3(FFD * DIMD / 1024), 256, 0, stream>>>(w1, w1h);
    cast_f32_f16<<<dim3(FFD * DIMD / 1024), 256, 0, stream>>>(w2, w2h);
    ln_kernel<<<dim3(MROWS), 256, 0, stream>>>(x, ln1w, ln1b, h, nullptr, 1);
    scan_partial<<<dim3(DIMD / 256, CHUNKS, BATCH), 256, 0, stream>>>(h, pre, pim, e);
    scan_combine<<<dim3(DIMD / 256, BATCH), 256, 0, stream>>>(e, pre, pim, lre, lim, sv);
    scan_final<<<dim3(DIMD / 256, CHUNKS, BATCH), 256, 0, stream>>>(h, x, pre, pim, sc, sv, x2);
    ln_kernel<<<dim3(MROWS), 256, 0, stream>>>(x2, ln2w, ln2b, nullptr, h2, 2);
    gemm_bt<<<dim3(FFD / BN, MROWS / BM), 256, 0, stream>>>(
        h2, w1h, b1, y1, nullptr, nullptr, FFD, DIMD, 1);
    gemm_bt<<<dim3(DIMD / BN, MROWS / BM), 256, 0, stream>>>(
        y1, w2h, b2, nullptr, x2, outp, DIMD, FFD, 2);
}

// Round 2
// 382.428 us; speedup vs baseline: 1.0340x; 1.0340x over previous
//
#include <hip/hip_runtime.h>
#include <cmath>

// ---------------------------------------------------------------------------
// SConvNetBlock: LN1 -> SiLU -> complex-decay scan (== reference FFT conv)
//                -> *sc_lin -> +res -> LN2 -> FFN(GEMM+SiLU+GEMM) -> +res
// Design notes:
//  * sconv: c[l] = p*c[l-1] + h[l], c[-1]=last, out = Re(c).  Chunked scan.
//  * GEMMs fp16 MFMA 16x16x32, fp32 acc, 128x128 tile, BK=64.
//    Staging via global_load_lds width=16 (m97-style). LDS unpadded [128][64]
//    with XOR swizzle done on the GLOBAL side: LDS slot (row, cc) holds global
//    chunk cc ^ (row&7). Fragment ds_read_b128 at slot ((kk/8+quad)^(fr&7))
//    -> each 8-lane group covers all 32 banks once (conflict-free), and the
//    staging loads stay fully coalesced (chunks permute within a 128B row
//    segment).
//  * x2 stored in d_out (fully written before LN2/GEMM2 read it).
// ---------------------------------------------------------------------------

#define DIMD 1024
#define FFD  4096
#define BATCH 4
#define SEQL 2048
#define MROWS (BATCH*SEQL)      // 8192
#define EPSF 1e-5f
#define CHUNKS 32
#define CLEN (SEQL/CHUNKS)      // 64

typedef __attribute__((ext_vector_type(8))) _Float16 half8;
typedef __attribute__((ext_vector_type(4))) _Float16 half4;
typedef __attribute__((ext_vector_type(4))) float    floatx4;

// ---- workspace layout (bytes) ----
#define H_OFF    0u                       // h   fp32 [8192][1024]   32 MB
#define E_OFF    33554432u                // e   float2 [4][32][1024] 1 MB
#define SIN_OFF  34603008u                // sin float2 [4][32][1024] 1 MB
#define H2_OFF   35651584u                // h2  fp16 [8192][1024]   16 MB
#define W1H_OFF  52428800u                // w1h fp16 [4096][1024]    8 MB
#define W2H_OFF  60817408u                // w2h fp16 [1024][4096]    8 MB
#define Y1_OFF   69206016u                // y1  fp16 [8192][4096]   64 MB
// total ~130 MB

__device__ __forceinline__ void load_lds16(const _Float16* g, _Float16* l) {
    __builtin_amdgcn_global_load_lds(
        (const __attribute__((address_space(1))) unsigned int*)g,
        (__attribute__((address_space(3))) unsigned int*)l,
        16, 0, 0);
}

__global__ __launch_bounds__(256)
void cast_f32_f16(const float* __restrict__ src, _Float16* __restrict__ dst) {
    int i = (blockIdx.x * 256 + threadIdx.x) * 4;
    float4 v = *(const float4*)(src + i);
    half4 o;
    o.x = (_Float16)v.x; o.y = (_Float16)v.y; o.z = (_Float16)v.z; o.w = (_Float16)v.w;
    *(half4*)(dst + i) = o;
}

// mode 1: out = silu(LN(x)) fp32 ;  mode 2: out = LN(x) fp16
__global__ __launch_bounds__(256)
void ln_kernel(const float* __restrict__ x, const float* __restrict__ w,
               const float* __restrict__ b, float* __restrict__ of,
               _Float16* __restrict__ oh, int mode) {
    const size_t row = blockIdx.x;
    const int tid = threadIdx.x;
    float4 v = *(const float4*)(x + row * DIMD + tid * 4);
    float s = (v.x + v.y) + (v.z + v.w);
    float q = (v.x * v.x + v.y * v.y) + (v.z * v.z + v.w * v.w);
    #pragma unroll
    for (int off = 32; off; off >>= 1) {
        s += __shfl_down(s, off, 64);
        q += __shfl_down(q, off, 64);
    }
    __shared__ float red[8];
    if (!(tid & 63)) { red[tid >> 6] = s; red[4 + (tid >> 6)] = q; }
    __syncthreads();
    s = (red[0] + red[1]) + (red[2] + red[3]);
    q = (red[4] + red[5]) + (red[6] + red[7]);
    const float mu = s * (1.f / DIMD);
    const float rs = rsqrtf(q * (1.f / DIMD) - mu * mu + EPSF);
    float4 wv = *(const float4*)(w + tid * 4);
    float4 bv = *(const float4*)(b + tid * 4);
    float o0 = (v.x - mu) * rs * wv.x + bv.x;
    float o1 = (v.y - mu) * rs * wv.y + bv.y;
    float o2 = (v.z - mu) * rs * wv.z + bv.z;
    float o3 = (v.w - mu) * rs * wv.w + bv.w;
    if (mode == 1) {
        o0 = o0 / (1.f + __expf(-o0));
        o1 = o1 / (1.f + __expf(-o1));
        o2 = o2 / (1.f + __expf(-o2));
        o3 = o3 / (1.f + __expf(-o3));
        float4 ov = {o0, o1, o2, o3};
        *(float4*)(of + row * DIMD + tid * 4) = ov;
    } else {
        half4 hv;
        hv.x = (_Float16)o0; hv.y = (_Float16)o1;
        hv.z = (_Float16)o2; hv.w = (_Float16)o3;
        *(half4*)(oh + row * DIMD + tid * 4) = hv;
    }
}

__device__ __forceinline__ void get_p(const float* pre, const float* pim, int d,
                                      float& pr, float& pi) {
    float re = pre[d], im = pim[d];
    float r = sqrtf(re * re + im * im);
    float t = tanhf(r) / fmaxf(r, 1e-30f);
    pr = re * t; pi = im * t;
}

// per-chunk local scan (zero initial state) -> end state e[b][c][d]
__global__ __launch_bounds__(256)
void scan_partial(const float* __restrict__ h, const float* __restrict__ pre,
                  const float* __restrict__ pim, float2* __restrict__ e) {
    const int d = blockIdx.x * 256 + threadIdx.x;
    const int c = blockIdx.y;
    const int bb = blockIdx.z;
    float pr, pi; get_p(pre, pim, d, pr, pi);
    float sr = 0.f, si = 0.f;
    const float* hp = h + ((size_t)bb * SEQL + (size_t)c * CLEN) * DIMD + d;
    #pragma unroll 4
    for (int j = 0; j < CLEN; ++j) {
        float hv = hp[(size_t)j * DIMD];
        float nr = pr * sr - pi * si + hv;
        float ni = pr * si + pi * sr;
        sr = nr; si = ni;
    }
    e[((size_t)bb * CHUNKS + c) * DIMD + d] = make_float2(sr, si);
}

// sequential combine over chunks: sin[b][c][d] = state entering chunk c
__global__ __launch_bounds__(256)
void scan_combine(const float2* __restrict__ e, const float* __restrict__ pre,
                  const float* __restrict__ pim, const float* __restrict__ lre,
                  const float* __restrict__ lim, float2* __restrict__ sv) {
    const int d = blockIdx.x * 256 + threadIdx.x;
    const int bb = blockIdx.y;
    float pr, pi; get_p(pre, pim, d, pr, pi);
    float qr = pr, qi = pi;                 // p^64 via 6 squarings
    #pragma unroll
    for (int s = 0; s < 6; ++s) {
        float nr = qr * qr - qi * qi;
        float ni = 2.f * qr * qi;
        qr = nr; qi = ni;
    }
    float sr = lre[d], si = lim[d];
    for (int c = 0; c < CHUNKS; ++c) {
        sv[((size_t)bb * CHUNKS + c) * DIMD + d] = make_float2(sr, si);
        float2 ec = e[((size_t)bb * CHUNKS + c) * DIMD + d];
        float nr = qr * sr - qi * si + ec.x;
        float ni = qr * si + qi * sr + ec.y;
        sr = nr; si = ni;
    }
}

// final scan with true incoming state; x2 = x + sc*Re(c) -> d_out
__global__ __launch_bounds__(256)
void scan_final(const float* __restrict__ h, const float* __restrict__ x,
                const float* __restrict__ pre, const float* __restrict__ pim,
                const float* __restrict__ sc, const float2* __restrict__ sv,
                float* __restrict__ x2) {
    const int d = blockIdx.x * 256 + threadIdx.x;
    const int c = blockIdx.y;
    const int bb = blockIdx.z;
    float pr, pi; get_p(pre, pim, d, pr, pi);
    float2 s0 = sv[((size_t)bb * CHUNKS + c) * DIMD + d];
    float sr = s0.x, si = s0.y;
    const float scd = sc[d];
    const size_t base = ((size_t)bb * SEQL + (size_t)c * CLEN) * DIMD + d;
    #pragma unroll 4
    for (int j = 0; j < CLEN; ++j) {
        float hv = h[base + (size_t)j * DIMD];
        float nr = pr * sr - pi * si + hv;
        float ni = pr * si + pi * sr;
        sr = nr; si = ni;
        x2[base + (size_t)j * DIMD] = x[base + (size_t)j * DIMD] + scd * sr;
    }
}

// ---- GEMM: C[M][N] = A[M][K] * W[N][K]^T, fp16 in, fp32 acc ----
#define BM 128
#define BN 128
#define BK 64

__global__ __launch_bounds__(256)
void gemm_bt(const _Float16* __restrict__ A, const _Float16* __restrict__ W,
             const float* __restrict__ bias, _Float16* __restrict__ out_h,
             const float* resid, float* out_f, int N, int K, int epi) {
    __shared__ _Float16 As[BM * BK];
    __shared__ _Float16 Bs[BN * BK];
    const int tid  = threadIdx.x;
    const int lane = tid & 63;
    const int wave = tid >> 6;
    const int wm = (wave >> 1) * 64;
    const int wn = (wave & 1) * 64;
    const size_t m0 = (size_t)blockIdx.y * BM;
    const size_t n0 = (size_t)blockIdx.x * BN;
    const int fr = lane & 15;
    const int quad = lane >> 4;

    // staging: wave handles rows [wave*32, wave*32+32); each issue = 8 rows.
    // LDS slot (row, cc) <- global chunk cc ^ (row&7); row&7 == lane>>3.
    const int srow = wave * 32 + (lane >> 3);
    const int ccp  = ((lane & 7) ^ (lane >> 3)) * 8;   // swizzled global chunk (halfs)
    const _Float16* ag = A + (m0 + srow) * (size_t)K + ccp;
    const _Float16* wg = W + (n0 + srow) * (size_t)K + ccp;
    _Float16* asl = &As[(wave * 32) * BK];
    _Float16* bsl = &Bs[(wave * 32) * BK];

    floatx4 acc[4][4] = {};

    for (int k0 = 0; k0 < K; k0 += BK) {
        #pragma unroll
        for (int t = 0; t < 4; ++t) {
            load_lds16(ag + k0 + (size_t)(t * 8) * K, asl + t * 8 * BK);
            load_lds16(wg + k0 + (size_t)(t * 8) * K, bsl + t * 8 * BK);
        }
        __syncthreads();
        #pragma unroll
        for (int kk = 0; kk < BK; kk += 32) {
            half8 af[4], bf[4];
            #pragma unroll
            for (int i = 0; i < 4; ++i) {
                const int slot = (((kk >> 3) + quad) ^ (fr & 7)) * 8;
                af[i] = *(const half8*)(&As[(wm + i * 16 + fr) * BK + slot]);
                bf[i] = *(const half8*)(&Bs[(wn + i * 16 + fr) * BK + slot]);
            }
            #pragma unroll
            for (int i = 0; i < 4; ++i)
                #pragma unroll
                for (int j = 0; j < 4; ++j)
                    acc[i][j] = __builtin_amdgcn_mfma_f32_16x16x32_f16(
                        af[i], bf[j], acc[i][j], 0, 0, 0);
        }
        __syncthreads();
    }

    #pragma unroll
    for (int i = 0; i < 4; ++i) {
        #pragma unroll
        for (int j = 0; j < 4; ++j) {
            #pragma unroll
            for (int r = 0; r < 4; ++r) {
                const size_t gm = m0 + wm + i * 16 + quad * 4 + r;
                const size_t gn = n0 + wn + j * 16 + fr;
                float v = acc[i][j][r] + bias[gn];
                if (epi == 1) {
                    float sl = v / (1.f + __expf(-v));
                    out_h[gm * N + gn] = (_Float16)sl;
                } else {
                    out_f[gm * N + gn] = v + resid[gm * N + gn];
                }
            }
        }
    }
}

extern "C" void kernel_launch(void* const* d_in, const int* in_sizes, int n_in,
                              void* d_out, int out_size, void* d_ws, size_t ws_size,
                              hipStream_t stream) {
    const float* x    = (const float*)d_in[0];
    const float* ln1w = (const float*)d_in[1];
    const float* ln1b = (const float*)d_in[2];
    const float* ln2w = (const float*)d_in[3];
    const float* ln2b = (const float*)d_in[4];
    const float* sc   = (const float*)d_in[5];
    const float* pre  = (const float*)d_in[6];
    const float* pim  = (const float*)d_in[7];
    const float* lre  = (const float*)d_in[8];
    const float* lim  = (const float*)d_in[9];
    const float* w1   = (const float*)d_in[10];
    const float* b1   = (const float*)d_in[11];
    const float* w2   = (const float*)d_in[12];
    const float* b2   = (const float*)d_in[13];

    char* ws = (char*)d_ws;
    float*      h   = (float*)(ws + H_OFF);
    float2*     e   = (float2*)(ws + E_OFF);
    float2*     sv  = (float2*)(ws + SIN_OFF);
    _Float16*   h2  = (_Float16*)(ws + H2_OFF);
    _Float16*   w1h = (_Float16*)(ws + W1H_OFF);
    _Float16*   w2h = (_Float16*)(ws + W2H_OFF);
    _Float16*   y1  = (_Float16*)(ws + Y1_OFF);
    float*      x2  = (float*)d_out;
    float*      outp = (float*)d_out;

    cast_f32_f16<<<dim3(FFD * DIMD / 1024), 256, 0, stream>>>(w1, w1h);
    cast_f32_f16<<<dim3(FFD * DIMD / 1024), 256, 0, stream>>>(w2, w2h);
    ln_kernel<<<dim3(MROWS), 256, 0, stream>>>(x, ln1w, ln1b, h, nullptr, 1);
    scan_partial<<<dim3(DIMD / 256, CHUNKS, BATCH), 256, 0, stream>>>(h, pre, pim, e);
    scan_combine<<<dim3(DIMD / 256, BATCH), 256, 0, stream>>>(e, pre, pim, lre, lim, sv);
    scan_final<<<dim3(DIMD / 256, CHUNKS, BATCH), 256, 0, stream>>>(h, x, pre, pim, sc, sv, x2);
    ln_kernel<<<dim3(MROWS), 256, 0, stream>>>(x2, ln2w, ln2b, nullptr, h2, 2);
    gemm_bt<<<dim3(FFD / BN, MROWS / BM), 256, 0, stream>>>(
        h2, w1h, b1, y1, nullptr, nullptr, FFD, DIMD, 1);
    gemm_bt<<<dim3(DIMD / BN, MROWS / BM), 256, 0, stream>>>(
        y1, w2h, b2, nullptr, x2, outp, DIMD, FFD, 2);
}